// Round 1
// baseline (107.594 us; speedup 1.0000x reference)
//
#include <hip/hip_runtime.h>
#include <hip/hip_bf16.h>

// NT-Xent loss, N=4096, D=256, fp32 inputs, fp32 scalar output.
// loss = mean_i [ log( sum_{j != i} exp(2*cos(zn_i, zn_j)) ) - 2*cos(zn_i, zn_pair(i)) ]
//
// k1: normalize rows -> bf16 zn in ws, fp32 inv-norms, zero rowsum
// k2: Gram-matrix row-wise sum of exp via 16x16x32 bf16 MFMA (flash-style, no 8192^2 matrix)
// k3: per-row contrib = log(rowsum - exp(diag)) - pair_sim   (fp32-exact pair term)
// k4: reduce 8192 contribs -> d_out[0]

#define NROWS 8192
#define NHALF 4096
#define DDIM  256

typedef __bf16 bf16;
typedef __bf16 bf16x4 __attribute__((ext_vector_type(4)));
typedef __bf16 bf16x8 __attribute__((ext_vector_type(8)));
typedef float  f32x4  __attribute__((ext_vector_type(4)));

__constant__ const float kTwoLog2e = 2.8853900817779268f;  // 2*log2(e): exp(2x)=exp2(kTwoLog2e*x)
__constant__ const float kLn2      = 0.6931471805599453f;

__device__ __forceinline__ const float* zrow(const float* z1, const float* z2, int r) {
  return (r < NHALF) ? (z1 + (size_t)r * DDIM) : (z2 + (size_t)(r - NHALF) * DDIM);
}

// ---------------- k1: normalize ----------------
__global__ void k_normalize(const float* __restrict__ z1, const float* __restrict__ z2,
                            bf16* __restrict__ zn, float* __restrict__ invn,
                            float* __restrict__ rowsum) {
  const int wave = threadIdx.x >> 6, lane = threadIdx.x & 63;
  const int row = blockIdx.x * 4 + wave;
  const float* src = zrow(z1, z2, row);
  f32x4 v = *(const f32x4*)(src + lane * 4);
  float ss = v.x * v.x + v.y * v.y + v.z * v.z + v.w * v.w;
#pragma unroll
  for (int off = 1; off < 64; off <<= 1) ss += __shfl_xor(ss, off);
  const float inv = 1.0f / fmaxf(sqrtf(ss), 1e-8f);
  bf16x4 o;
  o.x = (bf16)(v.x * inv); o.y = (bf16)(v.y * inv);
  o.z = (bf16)(v.z * inv); o.w = (bf16)(v.w * inv);
  *(bf16x4*)(zn + (size_t)row * DDIM + lane * 4) = o;
  if (lane == 0) { invn[row] = inv; rowsum[row] = 0.0f; }
}

// ---------------- k2: Gram row-sums of exp ----------------
// 512 threads = 8 waves. Block tile: BM=256 rows (32/wave, A in regs) x full K=256.
// Column loop: BN=64 cols staged in LDS (row-major, stride 528B -> 2-way-only bank aliasing),
// double-buffered. 8 col-splits x 32 row-blocks = 256 blocks.
#define BM 256
#define BN 64
#define CSPLIT 8
#define LDSB 528  // 512 + 16 bytes per staged row

__global__ __launch_bounds__(512, 2) void k_gram(const bf16* __restrict__ zn,
                                                 float* __restrict__ rowsum) {
  __shared__ __align__(16) unsigned char lds[2][BN * LDSB];
  const int tid  = threadIdx.x;
  const int wave = tid >> 6, lane = tid & 63;
  const int quad = lane >> 4, l15 = lane & 15;
  const int rowblk = blockIdx.x >> 3, csplit = blockIdx.x & 7;
  const int c0 = csplit * (NROWS / CSPLIT);
  const int iters = (NROWS / CSPLIT) / BN;  // 16

  // A fragments: wave owns rows rowblk*256 + wave*32 + {0..31}; K=256 in 8 frags per 16-row sub.
  bf16x8 a[2][8];
#pragma unroll
  for (int s = 0; s < 2; ++s) {
    const int row = rowblk * BM + wave * 32 + s * 16 + l15;
    const bf16x8* ap = (const bf16x8*)(zn + (size_t)row * DDIM);
#pragma unroll
    for (int k = 0; k < 8; ++k) a[s][k] = ap[k * 4 + quad];  // k*32 + quad*8 elements
  }

  // staging: 512 threads x 4 chunks of 16B = 64 rows x 512B
  const int tr = tid >> 3;  // staged row 0..63
  const int tc = tid & 7;   // chunk base 0..7

  uint4 g[4];
  {
    const unsigned char* gp = (const unsigned char*)(zn + (size_t)(c0 + tr) * DDIM);
#pragma unroll
    for (int j = 0; j < 4; ++j) g[j] = *(const uint4*)(gp + (tc + 8 * j) * 16);
  }
#pragma unroll
  for (int j = 0; j < 4; ++j)
    *(uint4*)(&lds[0][tr * LDSB + (tc + 8 * j) * 16]) = g[j];

  float sum[2][4] = {{0.f, 0.f, 0.f, 0.f}, {0.f, 0.f, 0.f, 0.f}};
  const f32x4 zero4 = {0.f, 0.f, 0.f, 0.f};

  for (int it = 0; it < iters; ++it) {
    __syncthreads();  // staged buf (it&1) ready; prior reads of buf ((it+1)&1) done
    const int cur = it & 1;
    if (it + 1 < iters) {
      const unsigned char* gp =
          (const unsigned char*)(zn + (size_t)(c0 + (it + 1) * BN + tr) * DDIM);
#pragma unroll
      for (int j = 0; j < 4; ++j) g[j] = *(const uint4*)(gp + (tc + 8 * j) * 16);
    }

    f32x4 acc[2][4];
#pragma unroll
    for (int s = 0; s < 2; ++s)
#pragma unroll
      for (int cs = 0; cs < 4; ++cs) acc[s][cs] = zero4;

#pragma unroll
    for (int k = 0; k < 8; ++k) {
      bf16x8 b[4];
#pragma unroll
      for (int cs = 0; cs < 4; ++cs)
        b[cs] = *(const bf16x8*)(&lds[cur][(cs * 16 + l15) * LDSB + k * 64 + quad * 16]);
#pragma unroll
      for (int s = 0; s < 2; ++s)
#pragma unroll
        for (int cs = 0; cs < 4; ++cs)
          acc[s][cs] = __builtin_amdgcn_mfma_f32_16x16x32_bf16(a[s][k], b[cs], acc[s][cs], 0, 0, 0);
    }

#pragma unroll
    for (int s = 0; s < 2; ++s)
#pragma unroll
      for (int cs = 0; cs < 4; ++cs)
#pragma unroll
        for (int r = 0; r < 4; ++r)
          sum[s][r] += __builtin_amdgcn_exp2f(acc[s][cs][r] * kTwoLog2e);

    if (it + 1 < iters) {
#pragma unroll
      for (int j = 0; j < 4; ++j)
        *(uint4*)(&lds[(it + 1) & 1][tr * LDSB + (tc + 8 * j) * 16]) = g[j];
    }
  }

  // C/D layout (m89-verified): element (row = quad*4 + r, col = l15). Reduce cols across quad's 16 lanes.
#pragma unroll
  for (int s = 0; s < 2; ++s)
#pragma unroll
    for (int r = 0; r < 4; ++r) {
      float v = sum[s][r];
      v += __shfl_xor(v, 1); v += __shfl_xor(v, 2);
      v += __shfl_xor(v, 4); v += __shfl_xor(v, 8);
      if (l15 == 0) {
        const int row = rowblk * BM + wave * 32 + s * 16 + quad * 4 + r;
        atomicAdd(&rowsum[row], v);  // 8 col-split adders per row, spread addresses
      }
    }
}

// ---------------- k3: per-row contribution ----------------
__global__ void k_finalize(const float* __restrict__ z1, const float* __restrict__ z2,
                           const bf16* __restrict__ zn, const float* __restrict__ invn,
                           const float* __restrict__ rowsum, float* __restrict__ contrib) {
  const int wave = threadIdx.x >> 6, lane = threadIdx.x & 63;
  const int row = blockIdx.x * 4 + wave;
  const int pr = (row < NHALF) ? row + NHALF : row - NHALF;

  f32x4 a4 = *(const f32x4*)(zrow(z1, z2, row) + lane * 4);
  f32x4 b4 = *(const f32x4*)(zrow(z1, z2, pr) + lane * 4);
  bf16x4 nb = *(const bf16x4*)(zn + (size_t)row * DDIM + lane * 4);

  float pd = a4.x * b4.x + a4.y * b4.y + a4.z * b4.z + a4.w * b4.w;
  float f0 = (float)nb.x, f1 = (float)nb.y, f2 = (float)nb.z, f3 = (float)nb.w;
  float nd = f0 * f0 + f1 * f1 + f2 * f2 + f3 * f3;
#pragma unroll
  for (int off = 1; off < 64; off <<= 1) {
    pd += __shfl_xor(pd, off);
    nd += __shfl_xor(nd, off);
  }
  if (lane == 0) {
    const float p = 2.0f * pd * invn[row] * invn[pr];               // exact fp32 pair sim
    const float dexp = __builtin_amdgcn_exp2f(kTwoLog2e * nd);      // the GEMM's diagonal term
    const float lse = __builtin_amdgcn_logf(rowsum[row] - dexp) * kLn2;
    contrib[row] = lse - p;
  }
}

// ---------------- k4: reduce 8192 contribs ----------------
__global__ void k_reduce(const float* __restrict__ contrib, float* __restrict__ out) {
  const int wave = threadIdx.x >> 6, lane = threadIdx.x & 63;
  float acc = 0.0f;
  for (int i = threadIdx.x; i < NROWS; i += 256) acc += contrib[i];
#pragma unroll
  for (int off = 1; off < 64; off <<= 1) acc += __shfl_xor(acc, off);
  __shared__ float wsum[4];
  if (lane == 0) wsum[wave] = acc;
  __syncthreads();
  if (threadIdx.x == 0)
    out[0] = (wsum[0] + wsum[1] + wsum[2] + wsum[3]) * (1.0f / (float)NROWS);
}

extern "C" void kernel_launch(void* const* d_in, const int* in_sizes, int n_in,
                              void* d_out, int out_size, void* d_ws, size_t ws_size,
                              hipStream_t stream) {
  const float* z1 = (const float*)d_in[0];
  const float* z2 = (const float*)d_in[1];
  unsigned char* ws = (unsigned char*)d_ws;

  // ws layout: zn bf16 [8192*256] (4 MB) | invn f32[8192] | rowsum f32[8192] | contrib f32[8192]
  bf16* zn = (bf16*)ws;
  float* invn = (float*)(ws + (size_t)NROWS * DDIM * sizeof(bf16));
  float* rowsum = invn + NROWS;
  float* contrib = rowsum + NROWS;

  hipLaunchKernelGGL(k_normalize, dim3(NROWS / 4), dim3(256), 0, stream, z1, z2, zn, invn, rowsum);
  hipLaunchKernelGGL(k_gram, dim3((NROWS / BM) * CSPLIT), dim3(512), 0, stream, zn, rowsum);
  hipLaunchKernelGGL(k_finalize, dim3(NROWS / 4), dim3(256), 0, stream, z1, z2, zn, invn, rowsum,
                     contrib);
  hipLaunchKernelGGL(k_reduce, dim3(1), dim3(256), 0, stream, contrib, (float*)d_out);
}